// Round 6
// baseline (440.165 us; speedup 1.0000x reference)
//
#include <hip/hip_runtime.h>
#include <hip/hip_bf16.h>

// GCN: 3-layer GraphConv, N=50000 nodes, E=600000 edges, feats 128->128->128->16.
// Atomic-free SpMM via per-call CSR build (dst-bucketed):
//   deg(int atomics) -> norms -> scan -> scatter ->
//   L0: spmm128_csr -> gemm128(+nd,+b0,relu)
//   L1: spmm128_csr -> gemm128(+nd,+b1,relu)
//   L2: transform16 (ns,@W2) -> spmm16_csr fused(nd,b2,sigmoid+1e-8) -> d_out

__global__ __launch_bounds__(256) void degree_kernel(
    const int* __restrict__ src, const int* __restrict__ dst,
    float* __restrict__ deg_out_f, int* __restrict__ cnt_in, int E) {
  int e = blockIdx.x * 256 + threadIdx.x;
  if (e < E) {
    atomicAdd(&deg_out_f[src[e]], 1.0f);
    atomicAdd(&cnt_in[dst[e]], 1);
  }
}

// norm_src = rsqrt(deg_out) (0 if 0); norm_dst from int in-degree counts.
__global__ __launch_bounds__(256) void norm_kernel(
    float* __restrict__ ns, const int* __restrict__ cnt_in,
    float* __restrict__ nd, int n) {
  int i = blockIdx.x * 256 + threadIdx.x;
  if (i < n) {
    float v = ns[i];
    ns[i] = (v > 0.0f) ? rsqrtf(v) : 0.0f;
    int c = cnt_in[i];
    nd[i] = (c > 0) ? rsqrtf((float)c) : 0.0f;
  }
}

// Exclusive prefix scan of cnt[0..n) -> row_start[0..n]; single block of 1024.
__global__ __launch_bounds__(1024) void scan_kernel(
    const int* __restrict__ cnt, int* __restrict__ row_start, int n) {
  __shared__ int sums[1024];
  const int t = threadIdx.x;
  const int chunk = (n + 1023) >> 10;
  const int beg = t * chunk;
  const int end = min(beg + chunk, n);
  int s = 0;
  for (int i = beg; i < end; ++i) s += cnt[i];
  sums[t] = s;
  __syncthreads();
  // Hillis-Steele inclusive scan
  for (int off = 1; off < 1024; off <<= 1) {
    int v = (t >= off) ? sums[t - off] : 0;
    __syncthreads();
    sums[t] += v;
    __syncthreads();
  }
  int prefix = (t == 0) ? 0 : sums[t - 1];
  for (int i = beg; i < end; ++i) {
    row_start[i] = prefix;
    prefix += cnt[i];
  }
  if (t == 0) row_start[n] = sums[1023];
}

__global__ __launch_bounds__(256) void scatter_kernel(
    const int* __restrict__ src, const int* __restrict__ dst,
    const int* __restrict__ row_start, int* __restrict__ cursor,
    int* __restrict__ col_idx, int E) {
  int e = blockIdx.x * 256 + threadIdx.x;
  if (e < E) {
    int d = dst[e];
    int pos = row_start[d] + atomicAdd(&cursor[d], 1);
    col_idx[pos] = src[e];
  }
}

// agg[node][128] = sum over in-edges of h[src]*ns[src]. One wave per node,
// lane owns a float2. col/ns loaded lane-parallel per 64-edge chunk, shfl-bcast.
__global__ __launch_bounds__(256) void spmm128_csr(
    const float2* __restrict__ h2, const float* __restrict__ ns,
    const int* __restrict__ row_start, const int* __restrict__ col_idx,
    float2* __restrict__ agg2, int n) {
  const int node = blockIdx.x * 4 + (threadIdx.x >> 6);
  const int lane = threadIdx.x & 63;
  if (node >= n) return;
  const int beg = row_start[node];
  const int deg = row_start[node + 1] - beg;
  float2 acc = make_float2(0.f, 0.f);
  for (int base = 0; base < deg; base += 64) {
    const int m = min(64, deg - base);
    int colv = 0;
    float scv = 0.f;
    if (lane < m) {
      colv = col_idx[beg + base + lane];
      scv = ns[colv];
    }
    for (int j = 0; j < m; ++j) {
      int s = __shfl(colv, j);
      float sc = __shfl(scv, j);
      float2 v = h2[(size_t)s * 64 + lane];
      acc.x = fmaf(v.x, sc, acc.x);
      acc.y = fmaf(v.y, sc, acc.y);
    }
  }
  agg2[(size_t)node * 64 + lane] = acc;
}

// out[node][16] = sigmoid(segsum(t16[src]) * nd[node] + b2) + 1e-8.
// 16 lanes per node (4 nodes per wave), ns already folded into t16.
__global__ __launch_bounds__(256) void spmm16_csr_fused(
    const float* __restrict__ t16,
    const int* __restrict__ row_start, const int* __restrict__ col_idx,
    const float* __restrict__ nd, const float* __restrict__ b2,
    float* __restrict__ out, int n) {
  const int idx = blockIdx.x * 256 + threadIdx.x;
  const int node = idx >> 4;
  const int lane = idx & 15;
  if (node >= n) return;
  const int beg = row_start[node];
  const int deg = row_start[node + 1] - beg;
  float acc = 0.f;
  for (int base = 0; base < deg; base += 16) {
    const int m = min(16, deg - base);
    int colv = 0;
    if (lane < m) colv = col_idx[beg + base + lane];
    for (int j = 0; j < m; ++j) {
      int s = __shfl(colv, j, 16);
      acc += t16[(size_t)s * 16 + lane];
    }
  }
  float v = acc * nd[node] + b2[lane];
  out[(size_t)node * 16 + lane] = 1.0f / (1.0f + expf(-v)) + 1e-8f;
}

// C[n][128] = relu((A[n][128] * nd[row]) @ W[128][128] + b), K-tiled in LDS.
__global__ __launch_bounds__(256) void gemm128_relu(
    const float* __restrict__ A, const float* __restrict__ nd,
    const float* __restrict__ Wg, const float* __restrict__ bias,
    float* __restrict__ C, int n) {
  __shared__ float4 Wt[32][32];                 // [k][colchunk] 16 KB
  __shared__ __align__(16) float At[32][32];    // [row][k]      4 KB
  const int row0 = blockIdx.x * 32;
  const int chunk = threadIdx.x & 31;
  const int rsub = threadIdx.x >> 5;
  const float4* A4 = (const float4*)A;
  const float4* W4 = (const float4*)Wg;

  const float4 bb = ((const float4*)bias)[chunk];
  float4 acc[4];
#pragma unroll
  for (int j = 0; j < 4; ++j) acc[j] = bb;

  for (int kt = 0; kt < 4; ++kt) {
    for (int i = threadIdx.x; i < 32 * 32; i += 256) {
      int k = i >> 5, c = i & 31;
      Wt[k][c] = W4[(size_t)(kt * 32 + k) * 32 + c];
    }
    {
      int i = threadIdx.x;           // 256 threads == 32 rows x 8 float4
      int r = i >> 3, c4 = i & 7;
      int grow = row0 + r;
      float4 v = make_float4(0.f, 0.f, 0.f, 0.f);
      if (grow < n) {
        float s = nd[grow];
        v = A4[(size_t)grow * 32 + kt * 8 + c4];
        v.x *= s; v.y *= s; v.z *= s; v.w *= s;
      }
      ((float4*)At)[i] = v;
    }
    __syncthreads();
#pragma unroll
    for (int k = 0; k < 32; ++k) {
      float4 w = Wt[k][chunk];
#pragma unroll
      for (int j = 0; j < 4; ++j) {
        float a = At[rsub + 8 * j][k];
        acc[j].x = fmaf(a, w.x, acc[j].x);
        acc[j].y = fmaf(a, w.y, acc[j].y);
        acc[j].z = fmaf(a, w.z, acc[j].z);
        acc[j].w = fmaf(a, w.w, acc[j].w);
      }
    }
    __syncthreads();
  }
#pragma unroll
  for (int j = 0; j < 4; ++j) {
    int grow = row0 + rsub + 8 * j;
    if (grow < n) {
      float4 o = make_float4(fmaxf(acc[j].x, 0.f), fmaxf(acc[j].y, 0.f),
                             fmaxf(acc[j].z, 0.f), fmaxf(acc[j].w, 0.f));
      ((float4*)C)[(size_t)grow * 32 + chunk] = o;
    }
  }
}

// t16[n][16] = (A[n][128] * ns[row]) @ W2[128][16]   (transform-first, layer 2)
__global__ __launch_bounds__(256) void transform16_kernel(
    const float* __restrict__ A, const float* __restrict__ ns,
    const float* __restrict__ W2, float* __restrict__ out, int n) {
  __shared__ float Wsh[128 * 16];               // 8 KB
  __shared__ __align__(16) float Ash[16][128];  // 8 KB
  const int row0 = blockIdx.x * 16;
  for (int i = threadIdx.x; i < 128 * 16; i += 256) Wsh[i] = W2[i];
  const float4* A4 = (const float4*)A;
  for (int i = threadIdx.x; i < 16 * 32; i += 256) {
    int r = i >> 5;
    int c = i & 31;
    int grow = row0 + r;
    float4 v = make_float4(0.f, 0.f, 0.f, 0.f);
    if (grow < n) {
      float s = ns[grow];
      v = A4[(size_t)grow * 32 + c];
      v.x *= s; v.y *= s; v.z *= s; v.w *= s;
    }
    ((float4*)Ash)[i] = v;
  }
  __syncthreads();
  int r = threadIdx.x >> 4, c = threadIdx.x & 15;
  float acc = 0.f;
#pragma unroll
  for (int k = 0; k < 128; ++k) acc = fmaf(Ash[r][k], Wsh[k * 16 + c], acc);
  int grow = row0 + r;
  if (grow < n) out[(size_t)grow * 16 + c] = acc;
}

extern "C" void kernel_launch(void* const* d_in, const int* in_sizes, int n_in,
                              void* d_out, int out_size, void* d_ws, size_t ws_size,
                              hipStream_t stream) {
  const float* features = (const float*)d_in[0];
  const int* src = (const int*)d_in[1];
  const int* dst = (const int*)d_in[2];
  const float* W0 = (const float*)d_in[3];
  const float* b0 = (const float*)d_in[4];
  const float* W1 = (const float*)d_in[5];
  const float* b1 = (const float*)d_in[6];
  const float* W2 = (const float*)d_in[7];
  const float* b2 = (const float*)d_in[8];
  float* out = (float*)d_out;

  const int n = in_sizes[0] / 128;   // 50000
  const int E = in_sizes[1];         // 600000

  // Workspace layout (16B-aligned big buffers first):
  float* ws = (float*)d_ws;
  float* bufA = ws;                                  // n*128 f32
  float* bufB = bufA + (size_t)n * 128;              // n*128 f32
  float* norm_src = bufB + (size_t)n * 128;          // n f32   (deg_out -> rsqrt)
  int* cursor = (int*)(norm_src + n);                // n i32   (in-deg counts, then scatter cursor)
  float* norm_dst = (float*)(cursor + n);            // n f32
  int* row_start = (int*)(norm_dst + n);             // n+1 i32
  int* col_idx = row_start + (n + 1);                // E i32

  // --- CSR build + norms ---
  hipMemsetAsync(norm_src, 0, 2 * (size_t)n * sizeof(float), stream);  // norm_src + cursor
  degree_kernel<<<(E + 255) / 256, 256, 0, stream>>>(src, dst, norm_src, cursor, E);
  norm_kernel<<<(n + 255) / 256, 256, 0, stream>>>(norm_src, cursor, norm_dst, n);
  scan_kernel<<<1, 1024, 0, stream>>>(cursor, row_start, n);
  hipMemsetAsync(cursor, 0, (size_t)n * sizeof(int), stream);
  scatter_kernel<<<(E + 255) / 256, 256, 0, stream>>>(src, dst, row_start, cursor, col_idx, E);

  const int spmm_grid = (n + 3) / 4;      // 4 nodes (waves) per block
  const int gemm_grid = (n + 31) / 32;

  // layer 0
  spmm128_csr<<<spmm_grid, 256, 0, stream>>>(
      (const float2*)features, norm_src, row_start, col_idx, (float2*)bufB, n);
  gemm128_relu<<<gemm_grid, 256, 0, stream>>>(bufB, norm_dst, W0, b0, bufA, n);

  // layer 1
  spmm128_csr<<<spmm_grid, 256, 0, stream>>>(
      (const float2*)bufA, norm_src, row_start, col_idx, (float2*)bufB, n);
  gemm128_relu<<<gemm_grid, 256, 0, stream>>>(bufB, norm_dst, W1, b1, bufA, n);

  // layer 2: transform first (128->16), then CSR SpMM at d=16 fused with finalize
  transform16_kernel<<<(n + 15) / 16, 256, 0, stream>>>(bufA, norm_src, W2, bufB, n);
  spmm16_csr_fused<<<(n * 16 + 255) / 256, 256, 0, stream>>>(
      bufB, row_start, col_idx, norm_dst, b2, out, n);
}

// Round 8
// 370.752 us; speedup vs baseline: 1.1872x; 1.1872x over previous
//
#include <hip/hip_runtime.h>
#include <hip/hip_bf16.h>

// GCN: 3-layer GraphConv, N=50000 nodes, E=600000 edges, feats 128->128->128->16.
// Atomic-free SpMM via per-call CSR build (dst-bucketed):
//   deg(int atomics) -> norms -> 3-pass scan -> scatter(atomicSub) ->
//   L0: spmm128_csr -> gemm128(+nd,+b0,relu)
//   L1: spmm128_csr -> gemm128(+nd,+b1,relu)
//   L2: transform16 (ns,@W2) -> spmm16_csr fused(nd,b2,sigmoid+1e-8) -> d_out

#define SCAN_TILE 1024   // elements per scan block (256 threads x 4)

__global__ __launch_bounds__(256) void degree_kernel(
    const int* __restrict__ src, const int* __restrict__ dst,
    float* __restrict__ deg_out_f, int* __restrict__ cnt_in, int E) {
  int e = blockIdx.x * 256 + threadIdx.x;
  if (e < E) {
    atomicAdd(&deg_out_f[src[e]], 1.0f);
    atomicAdd(&cnt_in[dst[e]], 1);
  }
}

// norm_src = rsqrt(deg_out) (0 if 0); norm_dst from int in-degree counts.
__global__ __launch_bounds__(256) void norm_kernel(
    float* __restrict__ ns, const int* __restrict__ cnt_in,
    float* __restrict__ nd, int n) {
  int i = blockIdx.x * 256 + threadIdx.x;
  if (i < n) {
    float v = ns[i];
    ns[i] = (v > 0.0f) ? rsqrtf(v) : 0.0f;
    int c = cnt_in[i];
    nd[i] = (c > 0) ? rsqrtf((float)c) : 0.0f;
  }
}

// Scan pass A: per-block sums of SCAN_TILE elements.
__global__ __launch_bounds__(256) void scan_blocksums(
    const int* __restrict__ cnt, int* __restrict__ bsum, int n) {
  const int t = threadIdx.x;
  const int base = blockIdx.x * SCAN_TILE + t * 4;
  int s = 0;
#pragma unroll
  for (int k = 0; k < 4; ++k) {
    int i = base + k;
    if (i < n) s += cnt[i];
  }
  __shared__ int red[256];
  red[t] = s;
  __syncthreads();
  for (int off = 128; off > 0; off >>= 1) {
    if (t < off) red[t] += red[t + off];
    __syncthreads();
  }
  if (t == 0) bsum[blockIdx.x] = red[0];
}

// Scan pass B: exclusive-scan the (<=256) block sums in one block; total -> *rs_total.
__global__ __launch_bounds__(256) void scan_bsums(
    int* __restrict__ bsum, int nb, int* __restrict__ rs_total) {
  __shared__ int sh[256];
  const int t = threadIdx.x;
  const int v = (t < nb) ? bsum[t] : 0;
  sh[t] = v;
  __syncthreads();
  for (int off = 1; off < 256; off <<= 1) {
    int u = (t >= off) ? sh[t - off] : 0;
    __syncthreads();
    sh[t] += u;
    __syncthreads();
  }
  if (t < nb) bsum[t] = sh[t] - v;          // exclusive prefix
  if (t == 255) *rs_total = sh[255];        // == E -> row_start[n]
}

// Scan pass C: local exclusive scan + block offset -> row_start.
__global__ __launch_bounds__(256) void scan_final(
    const int* __restrict__ cnt, const int* __restrict__ bsum,
    int* __restrict__ row_start, int n) {
  const int t = threadIdx.x;
  const int base = blockIdx.x * SCAN_TILE + t * 4;
  int x[4];
#pragma unroll
  for (int k = 0; k < 4; ++k) {
    int i = base + k;
    x[k] = (i < n) ? cnt[i] : 0;
  }
  const int tsum = x[0] + x[1] + x[2] + x[3];
  __shared__ int sh[256];
  sh[t] = tsum;
  __syncthreads();
  for (int off = 1; off < 256; off <<= 1) {
    int u = (t >= off) ? sh[t - off] : 0;
    __syncthreads();
    sh[t] += u;
    __syncthreads();
  }
  int pre = sh[t] - tsum + bsum[blockIdx.x];
#pragma unroll
  for (int k = 0; k < 4; ++k) {
    int i = base + k;
    if (i < n) row_start[i] = pre;
    pre += x[k];
  }
}

// Scatter edges into CSR; consumes cursor counts via atomicSub (order-free).
__global__ __launch_bounds__(256) void scatter_kernel(
    const int* __restrict__ src, const int* __restrict__ dst,
    const int* __restrict__ row_start, int* __restrict__ cursor,
    int* __restrict__ col_idx, int E) {
  int e = blockIdx.x * 256 + threadIdx.x;
  if (e < E) {
    int d = dst[e];
    int pos = row_start[d] + atomicSub(&cursor[d], 1) - 1;
    col_idx[pos] = src[e];
  }
}

// agg[node][128] = sum over in-edges of h[src]*ns[src]. One wave per node,
// lane owns a float2. col/ns loaded lane-parallel per 64-edge chunk, shfl-bcast.
__global__ __launch_bounds__(256) void spmm128_csr(
    const float2* __restrict__ h2, const float* __restrict__ ns,
    const int* __restrict__ row_start, const int* __restrict__ col_idx,
    float2* __restrict__ agg2, int n) {
  const int node = blockIdx.x * 4 + (threadIdx.x >> 6);
  const int lane = threadIdx.x & 63;
  if (node >= n) return;
  const int beg = row_start[node];
  const int deg = row_start[node + 1] - beg;
  float2 acc = make_float2(0.f, 0.f);
  for (int base = 0; base < deg; base += 64) {
    const int m = min(64, deg - base);
    int colv = 0;
    float scv = 0.f;
    if (lane < m) {
      colv = col_idx[beg + base + lane];
      scv = ns[colv];
    }
    for (int j = 0; j < m; ++j) {
      int s = __shfl(colv, j);
      float sc = __shfl(scv, j);
      float2 v = h2[(size_t)s * 64 + lane];
      acc.x = fmaf(v.x, sc, acc.x);
      acc.y = fmaf(v.y, sc, acc.y);
    }
  }
  agg2[(size_t)node * 64 + lane] = acc;
}

// out[node][16] = sigmoid(segsum(t16[src]) * nd[node] + b2) + 1e-8.
// 16 lanes per node (4 nodes per wave), ns already folded into t16.
__global__ __launch_bounds__(256) void spmm16_csr_fused(
    const float* __restrict__ t16,
    const int* __restrict__ row_start, const int* __restrict__ col_idx,
    const float* __restrict__ nd, const float* __restrict__ b2,
    float* __restrict__ out, int n) {
  const int idx = blockIdx.x * 256 + threadIdx.x;
  const int node = idx >> 4;
  const int lane = idx & 15;
  if (node >= n) return;
  const int beg = row_start[node];
  const int deg = row_start[node + 1] - beg;
  float acc = 0.f;
  for (int base = 0; base < deg; base += 16) {
    const int m = min(16, deg - base);
    int colv = 0;
    if (lane < m) colv = col_idx[beg + base + lane];
    for (int j = 0; j < m; ++j) {
      int s = __shfl(colv, j, 16);
      acc += t16[(size_t)s * 16 + lane];
    }
  }
  float v = acc * nd[node] + b2[lane];
  out[(size_t)node * 16 + lane] = 1.0f / (1.0f + expf(-v)) + 1e-8f;
}

// C[n][128] = relu((A[n][128] * nd[row]) @ W[128][128] + b), K-tiled in LDS.
__global__ __launch_bounds__(256) void gemm128_relu(
    const float* __restrict__ A, const float* __restrict__ nd,
    const float* __restrict__ Wg, const float* __restrict__ bias,
    float* __restrict__ C, int n) {
  __shared__ float4 Wt[32][32];                 // [k][colchunk] 16 KB
  __shared__ __align__(16) float At[32][32];    // [row][k]      4 KB
  const int row0 = blockIdx.x * 32;
  const int chunk = threadIdx.x & 31;
  const int rsub = threadIdx.x >> 5;
  const float4* A4 = (const float4*)A;
  const float4* W4 = (const float4*)Wg;

  const float4 bb = ((const float4*)bias)[chunk];
  float4 acc[4];
#pragma unroll
  for (int j = 0; j < 4; ++j) acc[j] = bb;

  for (int kt = 0; kt < 4; ++kt) {
    for (int i = threadIdx.x; i < 32 * 32; i += 256) {
      int k = i >> 5, c = i & 31;
      Wt[k][c] = W4[(size_t)(kt * 32 + k) * 32 + c];
    }
    {
      int i = threadIdx.x;           // 256 threads == 32 rows x 8 float4
      int r = i >> 3, c4 = i & 7;
      int grow = row0 + r;
      float4 v = make_float4(0.f, 0.f, 0.f, 0.f);
      if (grow < n) {
        float s = nd[grow];
        v = A4[(size_t)grow * 32 + kt * 8 + c4];
        v.x *= s; v.y *= s; v.z *= s; v.w *= s;
      }
      ((float4*)At)[i] = v;
    }
    __syncthreads();
#pragma unroll
    for (int k = 0; k < 32; ++k) {
      float4 w = Wt[k][chunk];
#pragma unroll
      for (int j = 0; j < 4; ++j) {
        float a = At[rsub + 8 * j][k];
        acc[j].x = fmaf(a, w.x, acc[j].x);
        acc[j].y = fmaf(a, w.y, acc[j].y);
        acc[j].z = fmaf(a, w.z, acc[j].z);
        acc[j].w = fmaf(a, w.w, acc[j].w);
      }
    }
    __syncthreads();
  }
#pragma unroll
  for (int j = 0; j < 4; ++j) {
    int grow = row0 + rsub + 8 * j;
    if (grow < n) {
      float4 o = make_float4(fmaxf(acc[j].x, 0.f), fmaxf(acc[j].y, 0.f),
                             fmaxf(acc[j].z, 0.f), fmaxf(acc[j].w, 0.f));
      ((float4*)C)[(size_t)grow * 32 + chunk] = o;
    }
  }
}

// t16[n][16] = (A[n][128] * ns[row]) @ W2[128][16]   (transform-first, layer 2)
__global__ __launch_bounds__(256) void transform16_kernel(
    const float* __restrict__ A, const float* __restrict__ ns,
    const float* __restrict__ W2, float* __restrict__ out, int n) {
  __shared__ float Wsh[128 * 16];               // 8 KB
  __shared__ __align__(16) float Ash[16][128];  // 8 KB
  const int row0 = blockIdx.x * 16;
  for (int i = threadIdx.x; i < 128 * 16; i += 256) Wsh[i] = W2[i];
  const float4* A4 = (const float4*)A;
  for (int i = threadIdx.x; i < 16 * 32; i += 256) {
    int r = i >> 5;
    int c = i & 31;
    int grow = row0 + r;
    float4 v = make_float4(0.f, 0.f, 0.f, 0.f);
    if (grow < n) {
      float s = ns[grow];
      v = A4[(size_t)grow * 32 + c];
      v.x *= s; v.y *= s; v.z *= s; v.w *= s;
    }
    ((float4*)Ash)[i] = v;
  }
  __syncthreads();
  int r = threadIdx.x >> 4, c = threadIdx.x & 15;
  float acc = 0.f;
#pragma unroll
  for (int k = 0; k < 128; ++k) acc = fmaf(Ash[r][k], Wsh[k * 16 + c], acc);
  int grow = row0 + r;
  if (grow < n) out[(size_t)grow * 16 + c] = acc;
}

extern "C" void kernel_launch(void* const* d_in, const int* in_sizes, int n_in,
                              void* d_out, int out_size, void* d_ws, size_t ws_size,
                              hipStream_t stream) {
  const float* features = (const float*)d_in[0];
  const int* src = (const int*)d_in[1];
  const int* dst = (const int*)d_in[2];
  const float* W0 = (const float*)d_in[3];
  const float* b0 = (const float*)d_in[4];
  const float* W1 = (const float*)d_in[5];
  const float* b1 = (const float*)d_in[6];
  const float* W2 = (const float*)d_in[7];
  const float* b2 = (const float*)d_in[8];
  float* out = (float*)d_out;

  const int n = in_sizes[0] / 128;   // 50000
  const int E = in_sizes[1];         // 600000

  // Workspace layout (16B-aligned big buffers first):
  float* ws = (float*)d_ws;
  float* bufA = ws;                                  // n*128 f32
  float* bufB = bufA + (size_t)n * 128;              // n*128 f32
  float* norm_src = bufB + (size_t)n * 128;          // n f32   (deg_out -> rsqrt)
  int* cursor = (int*)(norm_src + n);                // n i32   (in-deg counts; scatter consumes)
  float* norm_dst = (float*)(cursor + n);            // n f32
  int* row_start = (int*)(norm_dst + n);             // n+1 i32
  int* col_idx = row_start + (n + 1);                // E i32
  int* bsum = col_idx + E;                           // <=256 i32 (scan partials)

  const int nscan = (n + SCAN_TILE - 1) / SCAN_TILE; // 49 blocks

  // --- CSR build + norms ---
  hipMemsetAsync(norm_src, 0, 2 * (size_t)n * sizeof(float), stream);  // norm_src + cursor
  degree_kernel<<<(E + 255) / 256, 256, 0, stream>>>(src, dst, norm_src, cursor, E);
  norm_kernel<<<(n + 255) / 256, 256, 0, stream>>>(norm_src, cursor, norm_dst, n);
  scan_blocksums<<<nscan, 256, 0, stream>>>(cursor, bsum, n);
  scan_bsums<<<1, 256, 0, stream>>>(bsum, nscan, row_start + n);
  scan_final<<<nscan, 256, 0, stream>>>(cursor, bsum, row_start, n);
  scatter_kernel<<<(E + 255) / 256, 256, 0, stream>>>(src, dst, row_start, cursor, col_idx, E);

  const int spmm_grid = (n + 3) / 4;      // 4 nodes (waves) per block
  const int gemm_grid = (n + 31) / 32;

  // layer 0
  spmm128_csr<<<spmm_grid, 256, 0, stream>>>(
      (const float2*)features, norm_src, row_start, col_idx, (float2*)bufB, n);
  gemm128_relu<<<gemm_grid, 256, 0, stream>>>(bufB, norm_dst, W0, b0, bufA, n);

  // layer 1
  spmm128_csr<<<spmm_grid, 256, 0, stream>>>(
      (const float2*)bufA, norm_src, row_start, col_idx, (float2*)bufB, n);
  gemm128_relu<<<gemm_grid, 256, 0, stream>>>(bufB, norm_dst, W1, b1, bufA, n);

  // layer 2: transform first (128->16), then CSR SpMM at d=16 fused with finalize
  transform16_kernel<<<(n + 15) / 16, 256, 0, stream>>>(bufA, norm_src, W2, bufB, n);
  spmm16_csr_fused<<<(n * 16 + 255) / 256, 256, 0, stream>>>(
      bufB, row_start, col_idx, norm_dst, b2, out, n);
}

// Round 11
// 353.217 us; speedup vs baseline: 1.2462x; 1.0496x over previous
//
#include <hip/hip_runtime.h>
#include <hip/hip_bf16.h>

// GCN: 3-layer GraphConv, N=50000 nodes, E=600000 edges, feats 128->128->128->16.
// CSR build with atomic-free histograms (LDS-packed u16, 2 nodes/word):
//   hist(src)->partialsA, hist(dst)->partialsB, reduce->(ns,nd,cnt),
//   3-pass scan -> scatter(atomicSub) ->
//   L0: spmm128_csr -> gemm128(+nd,+b0,relu)
//   L1: spmm128_csr -> gemm128(+nd,+b1,relu)
//   L2: transform16 (ns,@W2) -> spmm16_csr fused(nd,b2,sigmoid+1e-8) -> d_out

#define SCAN_TILE 1024   // elements per scan block (256 threads x 4)
#define HIST_P    64     // partial histograms
#define NW_MAX    25088  // max packed words (2 nodes/word) -> 100,352 B LDS

// Packed histogram: word v>>1, half v&1. Per-block edge count << 65536 -> no carry.
__global__ __launch_bounds__(256) void hist_pack(
    const int* __restrict__ idx, unsigned* __restrict__ partials, int E, int nw) {
  __shared__ unsigned sh[NW_MAX];
  const int t = threadIdx.x;
  for (int i = t; i < nw; i += 256) sh[i] = 0u;
  __syncthreads();
  const int per = (E + gridDim.x - 1) / gridDim.x;
  const int beg = blockIdx.x * per;
  const int end = min(E, beg + per);
  for (int i = beg + t; i < end; i += 256) {
    int v = idx[i];
    atomicAdd(&sh[v >> 1], 1u << ((v & 1) * 16));
  }
  __syncthreads();
  unsigned* outp = partials + (size_t)blockIdx.x * nw;
  for (int i = t; i < nw; i += 256) outp[i] = sh[i];
}

// Sum P partials; emit norm_src, norm_dst, and int in-degree counts for the scan.
__global__ __launch_bounds__(256) void reduce_hist(
    const unsigned* __restrict__ pa, const unsigned* __restrict__ pb,
    float* __restrict__ ns, float* __restrict__ nd, int* __restrict__ cnt, int nw) {
  const int w = blockIdx.x * 256 + threadIdx.x;
  if (w >= nw) return;
  unsigned sa = 0, sb = 0;
  for (int p = 0; p < HIST_P; ++p) {
    sa += pa[(size_t)p * nw + w];
    sb += pb[(size_t)p * nw + w];
  }
  unsigned a0 = sa & 0xffffu, a1 = sa >> 16;
  unsigned b0 = sb & 0xffffu, b1 = sb >> 16;
  ns[2 * w]     = a0 ? rsqrtf((float)a0) : 0.0f;
  ns[2 * w + 1] = a1 ? rsqrtf((float)a1) : 0.0f;
  nd[2 * w]     = b0 ? rsqrtf((float)b0) : 0.0f;
  nd[2 * w + 1] = b1 ? rsqrtf((float)b1) : 0.0f;
  cnt[2 * w] = (int)b0;
  cnt[2 * w + 1] = (int)b1;
}

// Scan pass A: per-block sums of SCAN_TILE elements.
__global__ __launch_bounds__(256) void scan_blocksums(
    const int* __restrict__ cnt, int* __restrict__ bsum, int n) {
  const int t = threadIdx.x;
  const int base = blockIdx.x * SCAN_TILE + t * 4;
  int s = 0;
#pragma unroll
  for (int k = 0; k < 4; ++k) {
    int i = base + k;
    if (i < n) s += cnt[i];
  }
  __shared__ int red[256];
  red[t] = s;
  __syncthreads();
  for (int off = 128; off > 0; off >>= 1) {
    if (t < off) red[t] += red[t + off];
    __syncthreads();
  }
  if (t == 0) bsum[blockIdx.x] = red[0];
}

// Scan pass B: exclusive-scan the (<=256) block sums; total -> *rs_total.
__global__ __launch_bounds__(256) void scan_bsums(
    int* __restrict__ bsum, int nb, int* __restrict__ rs_total) {
  __shared__ int sh[256];
  const int t = threadIdx.x;
  const int v = (t < nb) ? bsum[t] : 0;
  sh[t] = v;
  __syncthreads();
  for (int off = 1; off < 256; off <<= 1) {
    int u = (t >= off) ? sh[t - off] : 0;
    __syncthreads();
    sh[t] += u;
    __syncthreads();
  }
  if (t < nb) bsum[t] = sh[t] - v;          // exclusive prefix
  if (t == 255) *rs_total = sh[255];        // == E -> row_start[n]
}

// Scan pass C: local exclusive scan + block offset -> row_start.
__global__ __launch_bounds__(256) void scan_final(
    const int* __restrict__ cnt, const int* __restrict__ bsum,
    int* __restrict__ row_start, int n) {
  const int t = threadIdx.x;
  const int base = blockIdx.x * SCAN_TILE + t * 4;
  int x[4];
#pragma unroll
  for (int k = 0; k < 4; ++k) {
    int i = base + k;
    x[k] = (i < n) ? cnt[i] : 0;
  }
  const int tsum = x[0] + x[1] + x[2] + x[3];
  __shared__ int sh[256];
  sh[t] = tsum;
  __syncthreads();
  for (int off = 1; off < 256; off <<= 1) {
    int u = (t >= off) ? sh[t - off] : 0;
    __syncthreads();
    sh[t] += u;
    __syncthreads();
  }
  int pre = sh[t] - tsum + bsum[blockIdx.x];
#pragma unroll
  for (int k = 0; k < 4; ++k) {
    int i = base + k;
    if (i < n) row_start[i] = pre;
    pre += x[k];
  }
}

// Scatter edges into CSR; consumes cnt via atomicSub (order within segment free).
__global__ __launch_bounds__(256) void scatter_kernel(
    const int* __restrict__ src, const int* __restrict__ dst,
    const int* __restrict__ row_start, int* __restrict__ cnt,
    int* __restrict__ col_idx, int E) {
  int e = blockIdx.x * 256 + threadIdx.x;
  if (e < E) {
    int d = dst[e];
    int pos = row_start[d] + atomicSub(&cnt[d], 1) - 1;
    col_idx[pos] = src[e];
  }
}

// agg[node][128] = sum over in-edges of h[src]*ns[src]. One wave per node,
// lane owns a float2. col/ns loaded lane-parallel per 64-edge chunk, shfl-bcast.
__global__ __launch_bounds__(256) void spmm128_csr(
    const float2* __restrict__ h2, const float* __restrict__ ns,
    const int* __restrict__ row_start, const int* __restrict__ col_idx,
    float2* __restrict__ agg2, int n) {
  const int node = blockIdx.x * 4 + (threadIdx.x >> 6);
  const int lane = threadIdx.x & 63;
  if (node >= n) return;
  const int beg = row_start[node];
  const int deg = row_start[node + 1] - beg;
  float2 acc = make_float2(0.f, 0.f);
  for (int base = 0; base < deg; base += 64) {
    const int m = min(64, deg - base);
    int colv = 0;
    float scv = 0.f;
    if (lane < m) {
      colv = col_idx[beg + base + lane];
      scv = ns[colv];
    }
    for (int j = 0; j < m; ++j) {
      int s = __shfl(colv, j);
      float sc = __shfl(scv, j);
      float2 v = h2[(size_t)s * 64 + lane];
      acc.x = fmaf(v.x, sc, acc.x);
      acc.y = fmaf(v.y, sc, acc.y);
    }
  }
  agg2[(size_t)node * 64 + lane] = acc;
}

// out[node][16] = sigmoid(segsum(t16[src]) * nd[node] + b2) + 1e-8.
__global__ __launch_bounds__(256) void spmm16_csr_fused(
    const float* __restrict__ t16,
    const int* __restrict__ row_start, const int* __restrict__ col_idx,
    const float* __restrict__ nd, const float* __restrict__ b2,
    float* __restrict__ out, int n) {
  const int idx = blockIdx.x * 256 + threadIdx.x;
  const int node = idx >> 4;
  const int lane = idx & 15;
  if (node >= n) return;
  const int beg = row_start[node];
  const int deg = row_start[node + 1] - beg;
  float acc = 0.f;
  for (int base = 0; base < deg; base += 16) {
    const int m = min(16, deg - base);
    int colv = 0;
    if (lane < m) colv = col_idx[beg + base + lane];
    for (int j = 0; j < m; ++j) {
      int s = __shfl(colv, j, 16);
      acc += t16[(size_t)s * 16 + lane];
    }
  }
  float v = acc * nd[node] + b2[lane];
  out[(size_t)node * 16 + lane] = 1.0f / (1.0f + expf(-v)) + 1e-8f;
}

// C[n][128] = relu((A[n][128] * nd[row]) @ W[128][128] + b), K-tiled in LDS.
__global__ __launch_bounds__(256) void gemm128_relu(
    const float* __restrict__ A, const float* __restrict__ nd,
    const float* __restrict__ Wg, const float* __restrict__ bias,
    float* __restrict__ C, int n) {
  __shared__ float4 Wt[32][32];                 // [k][colchunk] 16 KB
  __shared__ __align__(16) float At[32][32];    // [row][k]      4 KB
  const int row0 = blockIdx.x * 32;
  const int chunk = threadIdx.x & 31;
  const int rsub = threadIdx.x >> 5;
  const float4* A4 = (const float4*)A;
  const float4* W4 = (const float4*)Wg;

  const float4 bb = ((const float4*)bias)[chunk];
  float4 acc[4];
#pragma unroll
  for (int j = 0; j < 4; ++j) acc[j] = bb;

  for (int kt = 0; kt < 4; ++kt) {
    for (int i = threadIdx.x; i < 32 * 32; i += 256) {
      int k = i >> 5, c = i & 31;
      Wt[k][c] = W4[(size_t)(kt * 32 + k) * 32 + c];
    }
    {
      int i = threadIdx.x;           // 256 threads == 32 rows x 8 float4
      int r = i >> 3, c4 = i & 7;
      int grow = row0 + r;
      float4 v = make_float4(0.f, 0.f, 0.f, 0.f);
      if (grow < n) {
        float s = nd[grow];
        v = A4[(size_t)grow * 32 + kt * 8 + c4];
        v.x *= s; v.y *= s; v.z *= s; v.w *= s;
      }
      ((float4*)At)[i] = v;
    }
    __syncthreads();
#pragma unroll
    for (int k = 0; k < 32; ++k) {
      float4 w = Wt[k][chunk];
#pragma unroll
      for (int j = 0; j < 4; ++j) {
        float a = At[rsub + 8 * j][k];
        acc[j].x = fmaf(a, w.x, acc[j].x);
        acc[j].y = fmaf(a, w.y, acc[j].y);
        acc[j].z = fmaf(a, w.z, acc[j].z);
        acc[j].w = fmaf(a, w.w, acc[j].w);
      }
    }
    __syncthreads();
  }
#pragma unroll
  for (int j = 0; j < 4; ++j) {
    int grow = row0 + rsub + 8 * j;
    if (grow < n) {
      float4 o = make_float4(fmaxf(acc[j].x, 0.f), fmaxf(acc[j].y, 0.f),
                             fmaxf(acc[j].z, 0.f), fmaxf(acc[j].w, 0.f));
      ((float4*)C)[(size_t)grow * 32 + chunk] = o;
    }
  }
}

// t16[n][16] = (A[n][128] * ns[row]) @ W2[128][16]   (transform-first, layer 2)
__global__ __launch_bounds__(256) void transform16_kernel(
    const float* __restrict__ A, const float* __restrict__ ns,
    const float* __restrict__ W2, float* __restrict__ out, int n) {
  __shared__ float Wsh[128 * 16];               // 8 KB
  __shared__ __align__(16) float Ash[16][128];  // 8 KB
  const int row0 = blockIdx.x * 16;
  for (int i = threadIdx.x; i < 128 * 16; i += 256) Wsh[i] = W2[i];
  const float4* A4 = (const float4*)A;
  for (int i = threadIdx.x; i < 16 * 32; i += 256) {
    int r = i >> 5;
    int c = i & 31;
    int grow = row0 + r;
    float4 v = make_float4(0.f, 0.f, 0.f, 0.f);
    if (grow < n) {
      float s = ns[grow];
      v = A4[(size_t)grow * 32 + c];
      v.x *= s; v.y *= s; v.z *= s; v.w *= s;
    }
    ((float4*)Ash)[i] = v;
  }
  __syncthreads();
  int r = threadIdx.x >> 4, c = threadIdx.x & 15;
  float acc = 0.f;
#pragma unroll
  for (int k = 0; k < 128; ++k) acc = fmaf(Ash[r][k], Wsh[k * 16 + c], acc);
  int grow = row0 + r;
  if (grow < n) out[(size_t)grow * 16 + c] = acc;
}

extern "C" void kernel_launch(void* const* d_in, const int* in_sizes, int n_in,
                              void* d_out, int out_size, void* d_ws, size_t ws_size,
                              hipStream_t stream) {
  const float* features = (const float*)d_in[0];
  const int* src = (const int*)d_in[1];
  const int* dst = (const int*)d_in[2];
  const float* W0 = (const float*)d_in[3];
  const float* b0 = (const float*)d_in[4];
  const float* W1 = (const float*)d_in[5];
  const float* b1 = (const float*)d_in[6];
  const float* W2 = (const float*)d_in[7];
  const float* b2 = (const float*)d_in[8];
  float* out = (float*)d_out;

  const int n = in_sizes[0] / 128;   // 50000
  const int E = in_sizes[1];         // 600000
  const int nw = (n + 1) / 2;        // packed words (25000)

  // Workspace layout (16B-aligned big buffers first):
  float* ws = (float*)d_ws;
  float* bufA = ws;                                  // n*128 f32
  float* bufB = bufA + (size_t)n * 128;              // n*128 f32
  float* norm_src = bufB + (size_t)n * 128;          // n f32
  int* cnt = (int*)(norm_src + n);                   // n i32 (in-deg; scatter consumes)
  float* norm_dst = (float*)(cnt + n);               // n f32
  int* row_start = (int*)(norm_dst + n);             // n+1 i32
  int* col_idx = row_start + (n + 1);                // E i32
  int* bsum = col_idx + E;                           // <=256 i32 (scan partials)
  // Histogram partials alias the (not-yet-used) feature buffers:
  unsigned* partialsA = (unsigned*)bufA;             // HIST_P * nw u32 (6.4 MB)
  unsigned* partialsB = (unsigned*)bufB;             // HIST_P * nw u32 (6.4 MB)

  const int nscan = (n + SCAN_TILE - 1) / SCAN_TILE; // 49 blocks

  // --- CSR build + norms (no global atomics for histograms, no memsets) ---
  hist_pack<<<HIST_P, 256, 0, stream>>>(src, partialsA, E, nw);
  hist_pack<<<HIST_P, 256, 0, stream>>>(dst, partialsB, E, nw);
  reduce_hist<<<(nw + 255) / 256, 256, 0, stream>>>(
      partialsA, partialsB, norm_src, norm_dst, cnt, nw);
  scan_blocksums<<<nscan, 256, 0, stream>>>(cnt, bsum, n);
  scan_bsums<<<1, 256, 0, stream>>>(bsum, nscan, row_start + n);
  scan_final<<<nscan, 256, 0, stream>>>(cnt, bsum, row_start, n);
  scatter_kernel<<<(E + 255) / 256, 256, 0, stream>>>(src, dst, row_start, cnt, col_idx, E);

  const int spmm_grid = (n + 3) / 4;      // 4 nodes (waves) per block
  const int gemm_grid = (n + 31) / 32;

  // layer 0
  spmm128_csr<<<spmm_grid, 256, 0, stream>>>(
      (const float2*)features, norm_src, row_start, col_idx, (float2*)bufB, n);
  gemm128_relu<<<gemm_grid, 256, 0, stream>>>(bufB, norm_dst, W0, b0, bufA, n);

  // layer 1
  spmm128_csr<<<spmm_grid, 256, 0, stream>>>(
      (const float2*)bufA, norm_src, row_start, col_idx, (float2*)bufB, n);
  gemm128_relu<<<gemm_grid, 256, 0, stream>>>(bufB, norm_dst, W1, b1, bufA, n);

  // layer 2: transform first (128->16), then CSR SpMM at d=16 fused with finalize
  transform16_kernel<<<(n + 15) / 16, 256, 0, stream>>>(bufA, norm_src, W2, bufB, n);
  spmm16_csr_fused<<<(n * 16 + 255) / 256, 256, 0, stream>>>(
      bufB, row_start, col_idx, norm_dst, b2, out, n);
}

// Round 14
// 346.208 us; speedup vs baseline: 1.2714x; 1.0202x over previous
//
#include <hip/hip_runtime.h>
#include <hip/hip_bf16.h>

// GCN: 3-layer GraphConv, N=50000, E=600000, feats 128->128->128->16.
// bf16 gather pipeline: the SpMM-gathered matrix h is stored as bf16 with the
// src-norm (ns) prefolded -> halves random-gather bytes and drops per-edge
// ns loads. Aggregation and GEMM accumulate in f32.
//   hist(src/dst) -> reduce(ns,nd,cnt) -> prescale(features*ns->bf16) ->
//   scan -> scatter ->
//   L0: spmm_bf16 -> gemm128(+nd,W0,b0,relu,*ns->bf16)
//   L1: spmm_bf16 -> gemm128(+nd,W1,b1,relu,*ns->bf16)
//   L2: transform16(bf16 in, @W2) -> spmm16 fused(nd,b2,sigmoid+1e-8) -> out

#define SCAN_TILE 1024
#define HIST_P    64
#define NW_MAX    25088  // packed hist words (2 nodes/word) -> 100 KB LDS

__device__ __forceinline__ unsigned short f2bf(float x) {
  unsigned u = __float_as_uint(x);
  u += 0x7fffu + ((u >> 16) & 1u);   // round-to-nearest-even
  return (unsigned short)(u >> 16);
}
__device__ __forceinline__ unsigned pack2(float lo, float hi) {
  return (unsigned)f2bf(lo) | ((unsigned)f2bf(hi) << 16);
}

// Packed histogram: word v>>1, half v&1. Per-block count << 65536 -> no carry.
__global__ __launch_bounds__(256) void hist_pack(
    const int* __restrict__ idx, unsigned* __restrict__ partials, int E, int nw) {
  __shared__ unsigned sh[NW_MAX];
  const int t = threadIdx.x;
  for (int i = t; i < nw; i += 256) sh[i] = 0u;
  __syncthreads();
  const int per = (E + gridDim.x - 1) / gridDim.x;
  const int beg = blockIdx.x * per;
  const int end = min(E, beg + per);
  for (int i = beg + t; i < end; i += 256) {
    int v = idx[i];
    atomicAdd(&sh[v >> 1], 1u << ((v & 1) * 16));
  }
  __syncthreads();
  unsigned* outp = partials + (size_t)blockIdx.x * nw;
  for (int i = t; i < nw; i += 256) outp[i] = sh[i];
}

__global__ __launch_bounds__(256) void reduce_hist(
    const unsigned* __restrict__ pa, const unsigned* __restrict__ pb,
    float* __restrict__ ns, float* __restrict__ nd, int* __restrict__ cnt, int nw) {
  const int w = blockIdx.x * 256 + threadIdx.x;
  if (w >= nw) return;
  unsigned sa = 0, sb = 0;
  for (int p = 0; p < HIST_P; ++p) {
    sa += pa[(size_t)p * nw + w];
    sb += pb[(size_t)p * nw + w];
  }
  unsigned a0 = sa & 0xffffu, a1 = sa >> 16;
  unsigned b0 = sb & 0xffffu, b1 = sb >> 16;
  ns[2 * w]     = a0 ? rsqrtf((float)a0) : 0.0f;
  ns[2 * w + 1] = a1 ? rsqrtf((float)a1) : 0.0f;
  nd[2 * w]     = b0 ? rsqrtf((float)b0) : 0.0f;
  nd[2 * w + 1] = b1 ? rsqrtf((float)b1) : 0.0f;
  cnt[2 * w] = (int)b0;
  cnt[2 * w + 1] = (int)b1;
}

// hb[i] (u32 = 2 bf16) = features[row] * ns[row], word i covers cols {2c,2c+1}.
__global__ __launch_bounds__(256) void prescale_bf16(
    const float2* __restrict__ f2, const float* __restrict__ ns,
    unsigned* __restrict__ hb, int nwords) {
  int i = blockIdx.x * 256 + threadIdx.x;
  if (i < nwords) {
    float s = ns[i >> 6];
    float2 v = f2[i];
    hb[i] = pack2(v.x * s, v.y * s);
  }
}

__global__ __launch_bounds__(256) void scan_blocksums(
    const int* __restrict__ cnt, int* __restrict__ bsum, int n) {
  const int t = threadIdx.x;
  const int base = blockIdx.x * SCAN_TILE + t * 4;
  int s = 0;
#pragma unroll
  for (int k = 0; k < 4; ++k) {
    int i = base + k;
    if (i < n) s += cnt[i];
  }
  __shared__ int red[256];
  red[t] = s;
  __syncthreads();
  for (int off = 128; off > 0; off >>= 1) {
    if (t < off) red[t] += red[t + off];
    __syncthreads();
  }
  if (t == 0) bsum[blockIdx.x] = red[0];
}

__global__ __launch_bounds__(256) void scan_bsums(
    int* __restrict__ bsum, int nb, int* __restrict__ rs_total) {
  __shared__ int sh[256];
  const int t = threadIdx.x;
  const int v = (t < nb) ? bsum[t] : 0;
  sh[t] = v;
  __syncthreads();
  for (int off = 1; off < 256; off <<= 1) {
    int u = (t >= off) ? sh[t - off] : 0;
    __syncthreads();
    sh[t] += u;
    __syncthreads();
  }
  if (t < nb) bsum[t] = sh[t] - v;
  if (t == 255) *rs_total = sh[255];
}

__global__ __launch_bounds__(256) void scan_final(
    const int* __restrict__ cnt, const int* __restrict__ bsum,
    int* __restrict__ row_start, int n) {
  const int t = threadIdx.x;
  const int base = blockIdx.x * SCAN_TILE + t * 4;
  int x[4];
#pragma unroll
  for (int k = 0; k < 4; ++k) {
    int i = base + k;
    x[k] = (i < n) ? cnt[i] : 0;
  }
  const int tsum = x[0] + x[1] + x[2] + x[3];
  __shared__ int sh[256];
  sh[t] = tsum;
  __syncthreads();
  for (int off = 1; off < 256; off <<= 1) {
    int u = (t >= off) ? sh[t - off] : 0;
    __syncthreads();
    sh[t] += u;
    __syncthreads();
  }
  int pre = sh[t] - tsum + bsum[blockIdx.x];
#pragma unroll
  for (int k = 0; k < 4; ++k) {
    int i = base + k;
    if (i < n) row_start[i] = pre;
    pre += x[k];
  }
}

__global__ __launch_bounds__(256) void scatter_kernel(
    const int* __restrict__ src, const int* __restrict__ dst,
    const int* __restrict__ row_start, int* __restrict__ cnt,
    int* __restrict__ col_idx, int E) {
  int e = blockIdx.x * 256 + threadIdx.x;
  if (e < E) {
    int d = dst[e];
    int pos = row_start[d] + atomicSub(&cnt[d], 1) - 1;
    col_idx[pos] = src[e];
  }
}

// agg[node][128] f32 = sum over in-edges of hb16[src] (ns prefolded).
// One wave per node; lane owns cols {2*lane, 2*lane+1} (one u32 load/edge).
__global__ __launch_bounds__(256) void spmm128_csr_bf16(
    const unsigned* __restrict__ hb, const int* __restrict__ row_start,
    const int* __restrict__ col_idx, float2* __restrict__ agg2, int n) {
  const int node = blockIdx.x * 4 + (threadIdx.x >> 6);
  const int lane = threadIdx.x & 63;
  if (node >= n) return;
  const int beg = row_start[node];
  const int deg = row_start[node + 1] - beg;
  float2 acc = make_float2(0.f, 0.f);
  for (int base = 0; base < deg; base += 64) {
    const int m = min(64, deg - base);
    int colv = (lane < m) ? col_idx[beg + base + lane] : 0;
    for (int j = 0; j < m; ++j) {
      int s = __shfl(colv, j);
      unsigned v = hb[(size_t)s * 64 + lane];
      acc.x += __uint_as_float(v << 16);
      acc.y += __uint_as_float(v & 0xffff0000u);
    }
  }
  agg2[(size_t)node * 64 + lane] = acc;
}

// out[node][16] = sigmoid(segsum(t16[src]) * nd + b2) + 1e-8.
__global__ __launch_bounds__(256) void spmm16_csr_fused(
    const float* __restrict__ t16,
    const int* __restrict__ row_start, const int* __restrict__ col_idx,
    const float* __restrict__ nd, const float* __restrict__ b2,
    float* __restrict__ out, int n) {
  const int idx = blockIdx.x * 256 + threadIdx.x;
  const int node = idx >> 4;
  const int lane = idx & 15;
  if (node >= n) return;
  const int beg = row_start[node];
  const int deg = row_start[node + 1] - beg;
  float acc = 0.f;
  for (int base = 0; base < deg; base += 16) {
    const int m = min(16, deg - base);
    int colv = 0;
    if (lane < m) colv = col_idx[beg + base + lane];
    for (int j = 0; j < m; ++j) {
      int s = __shfl(colv, j, 16);
      acc += t16[(size_t)s * 16 + lane];
    }
  }
  float v = acc * nd[node] + b2[lane];
  out[(size_t)node * 16 + lane] = 1.0f / (1.0f + expf(-v)) + 1e-8f;
}

// hb_out[n][128]bf16 = relu((A[n][128]f32 * nd) @ W + b) * ns   (K-tiled LDS)
__global__ __launch_bounds__(256) void gemm128_relu_bf16(
    const float* __restrict__ A, const float* __restrict__ nd,
    const float* __restrict__ Wg, const float* __restrict__ bias,
    const float* __restrict__ ns, unsigned* __restrict__ hb, int n) {
  __shared__ float4 Wt[32][32];
  __shared__ __align__(16) float At[32][32];
  const int row0 = blockIdx.x * 32;
  const int chunk = threadIdx.x & 31;
  const int rsub = threadIdx.x >> 5;
  const float4* A4 = (const float4*)A;
  const float4* W4 = (const float4*)Wg;

  const float4 bb = ((const float4*)bias)[chunk];
  float4 acc[4];
#pragma unroll
  for (int j = 0; j < 4; ++j) acc[j] = bb;

  for (int kt = 0; kt < 4; ++kt) {
    for (int i = threadIdx.x; i < 32 * 32; i += 256) {
      int k = i >> 5, c = i & 31;
      Wt[k][c] = W4[(size_t)(kt * 32 + k) * 32 + c];
    }
    {
      int i = threadIdx.x;
      int r = i >> 3, c4 = i & 7;
      int grow = row0 + r;
      float4 v = make_float4(0.f, 0.f, 0.f, 0.f);
      if (grow < n) {
        float s = nd[grow];
        v = A4[(size_t)grow * 32 + kt * 8 + c4];
        v.x *= s; v.y *= s; v.z *= s; v.w *= s;
      }
      ((float4*)At)[i] = v;
    }
    __syncthreads();
#pragma unroll
    for (int k = 0; k < 32; ++k) {
      float4 w = Wt[k][chunk];
#pragma unroll
      for (int j = 0; j < 4; ++j) {
        float a = At[rsub + 8 * j][k];
        acc[j].x = fmaf(a, w.x, acc[j].x);
        acc[j].y = fmaf(a, w.y, acc[j].y);
        acc[j].z = fmaf(a, w.z, acc[j].z);
        acc[j].w = fmaf(a, w.w, acc[j].w);
      }
    }
    __syncthreads();
  }
  uint2* hb2 = (uint2*)hb;
#pragma unroll
  for (int j = 0; j < 4; ++j) {
    int grow = row0 + rsub + 8 * j;
    if (grow < n) {
      float s = ns[grow];
      float ox = fmaxf(acc[j].x, 0.f) * s, oy = fmaxf(acc[j].y, 0.f) * s;
      float oz = fmaxf(acc[j].z, 0.f) * s, ow = fmaxf(acc[j].w, 0.f) * s;
      hb2[(size_t)grow * 32 + chunk] = make_uint2(pack2(ox, oy), pack2(oz, ow));
    }
  }
}

// t16[n][16]f32 = hb16[n][128] @ W2[128][16]   (ns already folded into hb)
__global__ __launch_bounds__(256) void transform16_bf16(
    const unsigned* __restrict__ hb, const float* __restrict__ W2,
    float* __restrict__ out, int n) {
  __shared__ float Wsh[128 * 16];
  __shared__ __align__(16) float Ash[16][128];
  const int row0 = blockIdx.x * 16;
  for (int i = threadIdx.x; i < 128 * 16; i += 256) Wsh[i] = W2[i];
  const uint2* hb2 = (const uint2*)hb;
  for (int i = threadIdx.x; i < 16 * 32; i += 256) {
    int r = i >> 5;
    int c4 = i & 31;
    int grow = row0 + r;
    float4 v = make_float4(0.f, 0.f, 0.f, 0.f);
    if (grow < n) {
      uint2 p = hb2[(size_t)grow * 32 + c4];
      v = make_float4(__uint_as_float(p.x << 16), __uint_as_float(p.x & 0xffff0000u),
                      __uint_as_float(p.y << 16), __uint_as_float(p.y & 0xffff0000u));
    }
    ((float4*)Ash)[i] = v;
  }
  __syncthreads();
  int r = threadIdx.x >> 4, c = threadIdx.x & 15;
  float acc = 0.f;
#pragma unroll
  for (int k = 0; k < 128; ++k) acc = fmaf(Ash[r][k], Wsh[k * 16 + c], acc);
  int grow = row0 + r;
  if (grow < n) out[(size_t)grow * 16 + c] = acc;
}

extern "C" void kernel_launch(void* const* d_in, const int* in_sizes, int n_in,
                              void* d_out, int out_size, void* d_ws, size_t ws_size,
                              hipStream_t stream) {
  const float* features = (const float*)d_in[0];
  const int* src = (const int*)d_in[1];
  const int* dst = (const int*)d_in[2];
  const float* W0 = (const float*)d_in[3];
  const float* b0 = (const float*)d_in[4];
  const float* W1 = (const float*)d_in[5];
  const float* b1 = (const float*)d_in[6];
  const float* W2 = (const float*)d_in[7];
  const float* b2 = (const float*)d_in[8];
  float* out = (float*)d_out;

  const int n = in_sizes[0] / 128;   // 50000
  const int E = in_sizes[1];         // 600000
  const int nw = (n + 1) / 2;        // packed hist words (25000)

  // Workspace layout:
  float* ws = (float*)d_ws;
  float* agg = ws;                                   // n*128 f32 (25.6 MB)
  unsigned* hb = (unsigned*)(agg + (size_t)n * 128); // n*64 u32 bf16 h (12.8 MB)
  float* t16 = (float*)(hb + (size_t)n * 64);        // n*16 f32
  float* norm_src = t16 + (size_t)n * 16;            // n f32
  int* cnt = (int*)(norm_src + n);                   // n i32
  float* norm_dst = (float*)(cnt + n);               // n f32
  int* row_start = (int*)(norm_dst + n);             // n+1 i32
  int* col_idx = row_start + (n + 1);                // E i32
  int* bsum = col_idx + E;                           // <=256 i32
  // Histogram partials alias agg (12.8 MB of its 25.6 MB):
  unsigned* partialsA = (unsigned*)agg;              // HIST_P*nw u32
  unsigned* partialsB = partialsA + (size_t)HIST_P * nw;

  const int nscan = (n + SCAN_TILE - 1) / SCAN_TILE;

  // --- CSR build + norms + feature prescale ---
  hist_pack<<<HIST_P, 256, 0, stream>>>(src, partialsA, E, nw);
  hist_pack<<<HIST_P, 256, 0, stream>>>(dst, partialsB, E, nw);
  reduce_hist<<<(nw + 255) / 256, 256, 0, stream>>>(
      partialsA, partialsB, norm_src, norm_dst, cnt, nw);
  prescale_bf16<<<(n * 64 + 255) / 256, 256, 0, stream>>>(
      (const float2*)features, norm_src, hb, n * 64);
  scan_blocksums<<<nscan, 256, 0, stream>>>(cnt, bsum, n);
  scan_bsums<<<1, 256, 0, stream>>>(bsum, nscan, row_start + n);
  scan_final<<<nscan, 256, 0, stream>>>(cnt, bsum, row_start, n);
  scatter_kernel<<<(E + 255) / 256, 256, 0, stream>>>(src, dst, row_start, cnt, col_idx, E);

  const int spmm_grid = (n + 3) / 4;
  const int gemm_grid = (n + 31) / 32;

  // layer 0
  spmm128_csr_bf16<<<spmm_grid, 256, 0, stream>>>(hb, row_start, col_idx, (float2*)agg, n);
  gemm128_relu_bf16<<<gemm_grid, 256, 0, stream>>>(agg, norm_dst, W0, b0, norm_src, hb, n);

  // layer 1
  spmm128_csr_bf16<<<spmm_grid, 256, 0, stream>>>(hb, row_start, col_idx, (float2*)agg, n);
  gemm128_relu_bf16<<<gemm_grid, 256, 0, stream>>>(agg, norm_dst, W1, b1, norm_src, hb, n);

  // layer 2: transform-first (128->16), then CSR SpMM + fused finalize
  transform16_bf16<<<(n + 15) / 16, 256, 0, stream>>>(hb, W2, t16, n);
  spmm16_csr_fused<<<(n * 16 + 255) / 256, 256, 0, stream>>>(
      t16, row_start, col_idx, norm_dst, b2, out, n);
}

// Round 17
// 306.212 us; speedup vs baseline: 1.4375x; 1.1306x over previous
//
#include <hip/hip_runtime.h>
#include <hip/hip_bf16.h>

// GCN: 3-layer GraphConv, N=50000, E=600000, feats 128->128->128->16.
// bf16 gather pipeline + 4-wide unrolled gathers (MLP fix: 4 independent
// loads in flight per wave instead of 1 -> covers L2/L3 latency).
//   hist(src/dst) -> reduce(ns,nd,cnt) -> prescale(features*ns->bf16) ->
//   scan -> scatter ->
//   L0: spmm_bf16 -> gemm128(+nd,W0,b0,relu,*ns->bf16)
//   L1: spmm_bf16 -> gemm128(+nd,W1,b1,relu,*ns->bf16)
//   L2: transform16(bf16 in, @W2) -> spmm16 fused(nd,b2,sigmoid+1e-8) -> out

#define SCAN_TILE 1024
#define HIST_P    64
#define NW_MAX    25088  // packed hist words (2 nodes/word) -> 100 KB LDS

__device__ __forceinline__ unsigned short f2bf(float x) {
  unsigned u = __float_as_uint(x);
  u += 0x7fffu + ((u >> 16) & 1u);   // round-to-nearest-even
  return (unsigned short)(u >> 16);
}
__device__ __forceinline__ unsigned pack2(float lo, float hi) {
  return (unsigned)f2bf(lo) | ((unsigned)f2bf(hi) << 16);
}

// Packed histogram: word v>>1, half v&1. Per-block count << 65536 -> no carry.
__global__ __launch_bounds__(256) void hist_pack(
    const int* __restrict__ idx, unsigned* __restrict__ partials, int E, int nw) {
  __shared__ unsigned sh[NW_MAX];
  const int t = threadIdx.x;
  for (int i = t; i < nw; i += 256) sh[i] = 0u;
  __syncthreads();
  const int per = (E + gridDim.x - 1) / gridDim.x;
  const int beg = blockIdx.x * per;
  const int end = min(E, beg + per);
  for (int i = beg + t; i < end; i += 256) {
    int v = idx[i];
    atomicAdd(&sh[v >> 1], 1u << ((v & 1) * 16));
  }
  __syncthreads();
  unsigned* outp = partials + (size_t)blockIdx.x * nw;
  for (int i = t; i < nw; i += 256) outp[i] = sh[i];
}

__global__ __launch_bounds__(256) void reduce_hist(
    const unsigned* __restrict__ pa, const unsigned* __restrict__ pb,
    float* __restrict__ ns, float* __restrict__ nd, int* __restrict__ cnt, int nw) {
  const int w = blockIdx.x * 256 + threadIdx.x;
  if (w >= nw) return;
  unsigned sa = 0, sb = 0;
  for (int p = 0; p < HIST_P; ++p) {
    sa += pa[(size_t)p * nw + w];
    sb += pb[(size_t)p * nw + w];
  }
  unsigned a0 = sa & 0xffffu, a1 = sa >> 16;
  unsigned b0 = sb & 0xffffu, b1 = sb >> 16;
  ns[2 * w]     = a0 ? rsqrtf((float)a0) : 0.0f;
  ns[2 * w + 1] = a1 ? rsqrtf((float)a1) : 0.0f;
  nd[2 * w]     = b0 ? rsqrtf((float)b0) : 0.0f;
  nd[2 * w + 1] = b1 ? rsqrtf((float)b1) : 0.0f;
  cnt[2 * w] = (int)b0;
  cnt[2 * w + 1] = (int)b1;
}

// hb[i] (u32 = 2 bf16) = features[row] * ns[row], word i covers cols {2c,2c+1}.
__global__ __launch_bounds__(256) void prescale_bf16(
    const float2* __restrict__ f2, const float* __restrict__ ns,
    unsigned* __restrict__ hb, int nwords) {
  int i = blockIdx.x * 256 + threadIdx.x;
  if (i < nwords) {
    float s = ns[i >> 6];
    float2 v = f2[i];
    hb[i] = pack2(v.x * s, v.y * s);
  }
}

__global__ __launch_bounds__(256) void scan_blocksums(
    const int* __restrict__ cnt, int* __restrict__ bsum, int n) {
  const int t = threadIdx.x;
  const int base = blockIdx.x * SCAN_TILE + t * 4;
  int s = 0;
#pragma unroll
  for (int k = 0; k < 4; ++k) {
    int i = base + k;
    if (i < n) s += cnt[i];
  }
  __shared__ int red[256];
  red[t] = s;
  __syncthreads();
  for (int off = 128; off > 0; off >>= 1) {
    if (t < off) red[t] += red[t + off];
    __syncthreads();
  }
  if (t == 0) bsum[blockIdx.x] = red[0];
}

__global__ __launch_bounds__(256) void scan_bsums(
    int* __restrict__ bsum, int nb, int* __restrict__ rs_total) {
  __shared__ int sh[256];
  const int t = threadIdx.x;
  const int v = (t < nb) ? bsum[t] : 0;
  sh[t] = v;
  __syncthreads();
  for (int off = 1; off < 256; off <<= 1) {
    int u = (t >= off) ? sh[t - off] : 0;
    __syncthreads();
    sh[t] += u;
    __syncthreads();
  }
  if (t < nb) bsum[t] = sh[t] - v;
  if (t == 255) *rs_total = sh[255];
}

__global__ __launch_bounds__(256) void scan_final(
    const int* __restrict__ cnt, const int* __restrict__ bsum,
    int* __restrict__ row_start, int n) {
  const int t = threadIdx.x;
  const int base = blockIdx.x * SCAN_TILE + t * 4;
  int x[4];
#pragma unroll
  for (int k = 0; k < 4; ++k) {
    int i = base + k;
    x[k] = (i < n) ? cnt[i] : 0;
  }
  const int tsum = x[0] + x[1] + x[2] + x[3];
  __shared__ int sh[256];
  sh[t] = tsum;
  __syncthreads();
  for (int off = 1; off < 256; off <<= 1) {
    int u = (t >= off) ? sh[t - off] : 0;
    __syncthreads();
    sh[t] += u;
    __syncthreads();
  }
  int pre = sh[t] - tsum + bsum[blockIdx.x];
#pragma unroll
  for (int k = 0; k < 4; ++k) {
    int i = base + k;
    if (i < n) row_start[i] = pre;
    pre += x[k];
  }
}

__global__ __launch_bounds__(256) void scatter_kernel(
    const int* __restrict__ src, const int* __restrict__ dst,
    const int* __restrict__ row_start, int* __restrict__ cnt,
    int* __restrict__ col_idx, int E) {
  int e = blockIdx.x * 256 + threadIdx.x;
  if (e < E) {
    int d = dst[e];
    int pos = row_start[d] + atomicSub(&cnt[d], 1) - 1;
    col_idx[pos] = src[e];
  }
}

// agg[node][128] f32 = sum over in-edges of hb16[src] (ns prefolded).
// One wave per node; lane owns cols {2*lane, 2*lane+1} (one u32 load/edge).
// Inner gather unrolled x4: 4 independent loads in flight per wave.
__global__ __launch_bounds__(256) void spmm128_csr_bf16(
    const unsigned* __restrict__ hb, const int* __restrict__ row_start,
    const int* __restrict__ col_idx, float2* __restrict__ agg2, int n) {
  const int node = blockIdx.x * 4 + (threadIdx.x >> 6);
  const int lane = threadIdx.x & 63;
  if (node >= n) return;
  const int beg = row_start[node];
  const int deg = row_start[node + 1] - beg;
  float2 acc = make_float2(0.f, 0.f);
  for (int base = 0; base < deg; base += 64) {
    const int m = min(64, deg - base);
    int colv = (lane < m) ? col_idx[beg + base + lane] : 0;
    int j = 0;
    for (; j + 4 <= m; j += 4) {
      int s0 = __shfl(colv, j);
      int s1 = __shfl(colv, j + 1);
      int s2 = __shfl(colv, j + 2);
      int s3 = __shfl(colv, j + 3);
      unsigned v0 = hb[(size_t)s0 * 64 + lane];
      unsigned v1 = hb[(size_t)s1 * 64 + lane];
      unsigned v2 = hb[(size_t)s2 * 64 + lane];
      unsigned v3 = hb[(size_t)s3 * 64 + lane];
      acc.x += __uint_as_float(v0 << 16);
      acc.y += __uint_as_float(v0 & 0xffff0000u);
      acc.x += __uint_as_float(v1 << 16);
      acc.y += __uint_as_float(v1 & 0xffff0000u);
      acc.x += __uint_as_float(v2 << 16);
      acc.y += __uint_as_float(v2 & 0xffff0000u);
      acc.x += __uint_as_float(v3 << 16);
      acc.y += __uint_as_float(v3 & 0xffff0000u);
    }
    for (; j < m; ++j) {
      int s = __shfl(colv, j);
      unsigned v = hb[(size_t)s * 64 + lane];
      acc.x += __uint_as_float(v << 16);
      acc.y += __uint_as_float(v & 0xffff0000u);
    }
  }
  agg2[(size_t)node * 64 + lane] = acc;
}

// out[node][16] = sigmoid(segsum(t16[src]) * nd + b2) + 1e-8.  Unrolled x4.
__global__ __launch_bounds__(256) void spmm16_csr_fused(
    const float* __restrict__ t16,
    const int* __restrict__ row_start, const int* __restrict__ col_idx,
    const float* __restrict__ nd, const float* __restrict__ b2,
    float* __restrict__ out, int n) {
  const int idx = blockIdx.x * 256 + threadIdx.x;
  const int node = idx >> 4;
  const int lane = idx & 15;
  if (node >= n) return;
  const int beg = row_start[node];
  const int deg = row_start[node + 1] - beg;
  float acc = 0.f;
  for (int base = 0; base < deg; base += 16) {
    const int m = min(16, deg - base);
    int colv = 0;
    if (lane < m) colv = col_idx[beg + base + lane];
    int j = 0;
    for (; j + 4 <= m; j += 4) {
      int s0 = __shfl(colv, j, 16);
      int s1 = __shfl(colv, j + 1, 16);
      int s2 = __shfl(colv, j + 2, 16);
      int s3 = __shfl(colv, j + 3, 16);
      float a0 = t16[(size_t)s0 * 16 + lane];
      float a1 = t16[(size_t)s1 * 16 + lane];
      float a2 = t16[(size_t)s2 * 16 + lane];
      float a3 = t16[(size_t)s3 * 16 + lane];
      acc += a0 + a1 + a2 + a3;
    }
    for (; j < m; ++j) {
      int s = __shfl(colv, j, 16);
      acc += t16[(size_t)s * 16 + lane];
    }
  }
  float v = acc * nd[node] + b2[lane];
  out[(size_t)node * 16 + lane] = 1.0f / (1.0f + expf(-v)) + 1e-8f;
}

// hb_out[n][128]bf16 = relu((A[n][128]f32 * nd) @ W + b) * ns   (K-tiled LDS)
__global__ __launch_bounds__(256) void gemm128_relu_bf16(
    const float* __restrict__ A, const float* __restrict__ nd,
    const float* __restrict__ Wg, const float* __restrict__ bias,
    const float* __restrict__ ns, unsigned* __restrict__ hb, int n) {
  __shared__ float4 Wt[32][32];
  __shared__ __align__(16) float At[32][32];
  const int row0 = blockIdx.x * 32;
  const int chunk = threadIdx.x & 31;
  const int rsub = threadIdx.x >> 5;
  const float4* A4 = (const float4*)A;
  const float4* W4 = (const float4*)Wg;

  const float4 bb = ((const float4*)bias)[chunk];
  float4 acc[4];
#pragma unroll
  for (int j = 0; j < 4; ++j) acc[j] = bb;

  for (int kt = 0; kt < 4; ++kt) {
    for (int i = threadIdx.x; i < 32 * 32; i += 256) {
      int k = i >> 5, c = i & 31;
      Wt[k][c] = W4[(size_t)(kt * 32 + k) * 32 + c];
    }
    {
      int i = threadIdx.x;
      int r = i >> 3, c4 = i & 7;
      int grow = row0 + r;
      float4 v = make_float4(0.f, 0.f, 0.f, 0.f);
      if (grow < n) {
        float s = nd[grow];
        v = A4[(size_t)grow * 32 + kt * 8 + c4];
        v.x *= s; v.y *= s; v.z *= s; v.w *= s;
      }
      ((float4*)At)[i] = v;
    }
    __syncthreads();
#pragma unroll
    for (int k = 0; k < 32; ++k) {
      float4 w = Wt[k][chunk];
#pragma unroll
      for (int j = 0; j < 4; ++j) {
        float a = At[rsub + 8 * j][k];
        acc[j].x = fmaf(a, w.x, acc[j].x);
        acc[j].y = fmaf(a, w.y, acc[j].y);
        acc[j].z = fmaf(a, w.z, acc[j].z);
        acc[j].w = fmaf(a, w.w, acc[j].w);
      }
    }
    __syncthreads();
  }
  uint2* hb2 = (uint2*)hb;
#pragma unroll
  for (int j = 0; j < 4; ++j) {
    int grow = row0 + rsub + 8 * j;
    if (grow < n) {
      float s = ns[grow];
      float ox = fmaxf(acc[j].x, 0.f) * s, oy = fmaxf(acc[j].y, 0.f) * s;
      float oz = fmaxf(acc[j].z, 0.f) * s, ow = fmaxf(acc[j].w, 0.f) * s;
      hb2[(size_t)grow * 32 + chunk] = make_uint2(pack2(ox, oy), pack2(oz, ow));
    }
  }
}

// t16[n][16]f32 = hb16[n][128] @ W2[128][16]   (ns already folded into hb)
__global__ __launch_bounds__(256) void transform16_bf16(
    const unsigned* __restrict__ hb, const float* __restrict__ W2,
    float* __restrict__ out, int n) {
  __shared__ float Wsh[128 * 16];
  __shared__ __align__(16) float Ash[16][128];
  const int row0 = blockIdx.x * 16;
  for (int i = threadIdx.x; i < 128 * 16; i += 256) Wsh[i] = W2[i];
  const uint2* hb2 = (const uint2*)hb;
  for (int i = threadIdx.x; i < 16 * 32; i += 256) {
    int r = i >> 5;
    int c4 = i & 31;
    int grow = row0 + r;
    float4 v = make_float4(0.f, 0.f, 0.f, 0.f);
    if (grow < n) {
      uint2 p = hb2[(size_t)grow * 32 + c4];
      v = make_float4(__uint_as_float(p.x << 16), __uint_as_float(p.x & 0xffff0000u),
                      __uint_as_float(p.y << 16), __uint_as_float(p.y & 0xffff0000u));
    }
    ((float4*)Ash)[i] = v;
  }
  __syncthreads();
  int r = threadIdx.x >> 4, c = threadIdx.x & 15;
  float acc = 0.f;
#pragma unroll
  for (int k = 0; k < 128; ++k) acc = fmaf(Ash[r][k], Wsh[k * 16 + c], acc);
  int grow = row0 + r;
  if (grow < n) out[(size_t)grow * 16 + c] = acc;
}

extern "C" void kernel_launch(void* const* d_in, const int* in_sizes, int n_in,
                              void* d_out, int out_size, void* d_ws, size_t ws_size,
                              hipStream_t stream) {
  const float* features = (const float*)d_in[0];
  const int* src = (const int*)d_in[1];
  const int* dst = (const int*)d_in[2];
  const float* W0 = (const float*)d_in[3];
  const float* b0 = (const float*)d_in[4];
  const float* W1 = (const float*)d_in[5];
  const float* b1 = (const float*)d_in[6];
  const float* W2 = (const float*)d_in[7];
  const float* b2 = (const float*)d_in[8];
  float* out = (float*)d_out;

  const int n = in_sizes[0] / 128;   // 50000
  const int E = in_sizes[1];         // 600000
  const int nw = (n + 1) / 2;        // packed hist words (25000)

  // Workspace layout:
  float* ws = (float*)d_ws;
  float* agg = ws;                                   // n*128 f32 (25.6 MB)
  unsigned* hb = (unsigned*)(agg + (size_t)n * 128); // n*64 u32 bf16 h (12.8 MB)
  float* t16 = (float*)(hb + (size_t)n * 64);        // n*16 f32
  float* norm_src = t16 + (size_t)n * 16;            // n f32
  int* cnt = (int*)(norm_src + n);                   // n i32
  float* norm_dst = (float*)(cnt + n);               // n f32
  int* row_start = (int*)(norm_dst + n);             // n+1 i32
  int* col_idx = row_start + (n + 1);                // E i32
  int* bsum = col_idx + E;                           // <=256 i32
  // Histogram partials alias agg (12.8 MB of its 25.6 MB):
  unsigned* partialsA = (unsigned*)agg;              // HIST_P*nw u32
  unsigned* partialsB = partialsA + (size_t)HIST_P * nw;

  const int nscan = (n + SCAN_TILE - 1) / SCAN_TILE;

  // --- CSR build + norms + feature prescale ---
  hist_pack<<<HIST_P, 256, 0, stream>>>(src, partialsA, E, nw);
  hist_pack<<<HIST_P, 256, 0, stream>>>(dst, partialsB, E, nw);
  reduce_hist<<<(nw + 255) / 256, 256, 0, stream>>>(
      partialsA, partialsB, norm_src, norm_dst, cnt, nw);
  prescale_bf16<<<(n * 64 + 255) / 256, 256, 0, stream>>>(
      (const float2*)features, norm_src, hb, n * 64);
  scan_blocksums<<<nscan, 256, 0, stream>>>(cnt, bsum, n);
  scan_bsums<<<1, 256, 0, stream>>>(bsum, nscan, row_start + n);
  scan_final<<<nscan, 256, 0, stream>>>(cnt, bsum, row_start, n);
  scatter_kernel<<<(E + 255) / 256, 256, 0, stream>>>(src, dst, row_start, cnt, col_idx, E);

  const int spmm_grid = (n + 3) / 4;
  const int gemm_grid = (n + 31) / 32;

  // layer 0
  spmm128_csr_bf16<<<spmm_grid, 256, 0, stream>>>(hb, row_start, col_idx, (float2*)agg, n);
  gemm128_relu_bf16<<<gemm_grid, 256, 0, stream>>>(agg, norm_dst, W0, b0, norm_src, hb, n);

  // layer 1
  spmm128_csr_bf16<<<spmm_grid, 256, 0, stream>>>(hb, row_start, col_idx, (float2*)agg, n);
  gemm128_relu_bf16<<<gemm_grid, 256, 0, stream>>>(agg, norm_dst, W1, b1, norm_src, hb, n);

  // layer 2: transform-first (128->16), then CSR SpMM + fused finalize
  transform16_bf16<<<(n + 15) / 16, 256, 0, stream>>>(hb, W2, t16, n);
  spmm16_csr_fused<<<(n * 16 + 255) / 256, 256, 0, stream>>>(
      t16, row_start, col_idx, norm_dst, b2, out, n);
}